// Round 1
// baseline (397.600 us; speedup 1.0000x reference)
//
#include <hip/hip_runtime.h>
#include <math.h>

#define B 8
#define LD 128
#define LP 1000
#define DIM 128
#define LN_EPS 1e-5f

// ---------------------------------------------------------------------------
// Kernel 1: out[row] = X[row] @ W^T + bias     (one block per row, DIM threads)
// ---------------------------------------------------------------------------
__global__ void gemv_rows(const float* __restrict__ X, const float* __restrict__ W,
                          const float* __restrict__ bias, float* __restrict__ out) {
    const int row = blockIdx.x;
    const int t = threadIdx.x;       // output dim
    __shared__ float xs[DIM];
    xs[t] = X[row * DIM + t];
    __syncthreads();

    const float4* w4 = reinterpret_cast<const float4*>(W + t * DIM);
    const float4* x4 = reinterpret_cast<const float4*>(xs);
    float acc = bias[t];
#pragma unroll
    for (int k = 0; k < DIM / 4; ++k) {
        float4 w = w4[k];
        float4 x = x4[k];
        acc += w.x * x.x + w.y * x.y + w.z * x.z + w.w * x.w;
    }
    out[row * DIM + t] = acc;
}

// ---------------------------------------------------------------------------
// Kernel 2: per (b,d): row/col sums of relu(x_i + y_j), i<LD, j<LP.
//   Mc[b,i,d] = (1/LP) * sum_j relu(x_i + y_j)    (mean over axis=2)
//   Mp[b,j,d] = (1/LD) * sum_i relu(x_i + y_j)    (mean over axis=1)
// 1024 blocks (b*DIM+d), 256 threads.
// ---------------------------------------------------------------------------
__global__ void pairwise(const float* __restrict__ d_att, const float* __restrict__ p_att,
                         float* __restrict__ Mc, float* __restrict__ Mp) {
    const int blk = blockIdx.x;
    const int b = blk >> 7;          // / DIM
    const int d = blk & (DIM - 1);
    const int t = threadIdx.x;

    __shared__ float xs[LD];
    __shared__ float ys[LP];
    __shared__ float red[256];

    for (int i = t; i < LD; i += 256) xs[i] = d_att[(b * LD + i) * DIM + d];
    for (int j = t; j < LP; j += 256) ys[j] = p_att[(b * LP + j) * DIM + d];
    __syncthreads();

    // column sums -> Mp  (each thread owns j = t, t+256, ...)
    for (int j = t; j < LP; j += 256) {
        const float y = ys[j];
        float s = 0.f;
#pragma unroll 8
        for (int i = 0; i < LD; ++i) s += fmaxf(0.f, xs[i] + y);
        Mp[(b * LP + j) * DIM + d] = s * (1.f / (float)LD);
    }

    // row sums -> Mc  (two threads per row, each covers 500 j's)
    {
        const int r = t & (LD - 1);
        const int h = t >> 7;        // 0 or 1
        const float x = xs[r];
        float s = 0.f;
        const int j0 = h * (LP / 2);
#pragma unroll 4
        for (int jj = 0; jj < LP / 2; ++jj) s += fmaxf(0.f, x + ys[j0 + jj]);
        red[t] = s;
    }
    __syncthreads();
    if (t < LD) {
        Mc[(b * LD + t) * DIM + d] = (red[t] + red[t + LD]) * (1.f / (float)LP);
    }
}

// ---------------------------------------------------------------------------
// Kernel 3: out[row] = conv[row] * (0.5 + sigmoid(M[row] @ W_att^T + b_att))
// ---------------------------------------------------------------------------
__global__ void gated_gemv(const float* __restrict__ M, const float* __restrict__ W,
                           const float* __restrict__ bias, const float* __restrict__ conv,
                           float* __restrict__ out) {
    const int row = blockIdx.x;
    const int t = threadIdx.x;
    __shared__ float xs[DIM];
    xs[t] = M[row * DIM + t];
    __syncthreads();

    const float4* w4 = reinterpret_cast<const float4*>(W + t * DIM);
    const float4* x4 = reinterpret_cast<const float4*>(xs);
    float acc = bias[t];
#pragma unroll
    for (int k = 0; k < DIM / 4; ++k) {
        float4 w = w4[k];
        float4 x = x4[k];
        acc += w.x * x.x + w.y * x.y + w.z * x.z + w.w * x.w;
    }
    const float att = 1.f / (1.f + expf(-acc));
    out[row * DIM + t] = conv[row * DIM + t] * (0.5f + att);
}

// ---------------------------------------------------------------------------
// Kernel 4: max over L then LayerNorm over DIM.
// 16 blocks: 0..7 = drug (L=LD), 8..15 = protein (L=LP). 128 threads.
// ---------------------------------------------------------------------------
__global__ void maxln(const float* __restrict__ gd, const float* __restrict__ gp,
                      const float* __restrict__ gamma1, const float* __restrict__ beta1,
                      const float* __restrict__ gamma2, const float* __restrict__ beta2,
                      float* __restrict__ out) {
    const int blk = blockIdx.x;
    const int kind = blk >> 3;       // 0 drug, 1 protein
    const int b = blk & 7;
    const int t = threadIdx.x;

    const float* src = kind ? gp : gd;
    const int L = kind ? LP : LD;
    const float* gamma = kind ? gamma2 : gamma1;
    const float* beta = kind ? beta2 : beta1;

    float m = -INFINITY;
    for (int i = 0; i < L; ++i) m = fmaxf(m, src[(b * L + i) * DIM + t]);

    __shared__ float s1[DIM];
    __shared__ float s2[DIM];
    s1[t] = m;
    s2[t] = m * m;
    __syncthreads();
    for (int off = DIM / 2; off > 0; off >>= 1) {
        if (t < off) { s1[t] += s1[t + off]; s2[t] += s2[t + off]; }
        __syncthreads();
    }
    const float mu = s1[0] * (1.f / (float)DIM);
    const float var = s2[0] * (1.f / (float)DIM) - mu * mu;
    const float inv = rsqrtf(var + LN_EPS);
    out[kind * (B * DIM) + b * DIM + t] = (m - mu) * inv * gamma[t] + beta[t];
}

// ---------------------------------------------------------------------------
extern "C" void kernel_launch(void* const* d_in, const int* in_sizes, int n_in,
                              void* d_out, int out_size, void* d_ws, size_t ws_size,
                              hipStream_t stream) {
    const float* drug_conv    = (const float*)d_in[0];   // (B, LD, DIM)
    const float* protein_conv = (const float*)d_in[1];   // (B, LP, DIM)
    const float* W_d   = (const float*)d_in[2];
    const float* b_d   = (const float*)d_in[3];
    const float* W_p   = (const float*)d_in[4];
    const float* b_p   = (const float*)d_in[5];
    const float* W_att = (const float*)d_in[6];
    const float* b_att = (const float*)d_in[7];
    const float* gamma1 = (const float*)d_in[8];
    const float* beta1  = (const float*)d_in[9];
    const float* gamma2 = (const float*)d_in[10];
    const float* beta2  = (const float*)d_in[11];
    float* out = (float*)d_out;

    // workspace layout (floats)
    float* ws = (float*)d_ws;
    const size_t n_datt = (size_t)B * LD * DIM;          // 131072
    const size_t n_patt = (size_t)B * LP * DIM;          // 1024000
    float* d_att = ws;                                   // [0, n_datt)
    float* p_att = ws + n_datt;                          // [n_datt, +n_patt)
    float* Mc    = ws + n_datt + n_patt;                 // (B,LD,DIM)
    float* Mp    = ws + n_datt + n_patt + n_datt;        // (B,LP,DIM)
    float* gd    = d_att;                                // alias: d_att dead after pairwise
    float* gp    = p_att;                                // alias: p_att dead after pairwise

    gemv_rows<<<B * LD, DIM, 0, stream>>>(drug_conv, W_d, b_d, d_att);
    gemv_rows<<<B * LP, DIM, 0, stream>>>(protein_conv, W_p, b_p, p_att);
    pairwise<<<B * DIM, 256, 0, stream>>>(d_att, p_att, Mc, Mp);
    gated_gemv<<<B * LD, DIM, 0, stream>>>(Mc, W_att, b_att, drug_conv, gd);
    gated_gemv<<<B * LP, DIM, 0, stream>>>(Mp, W_att, b_att, protein_conv, gp);
    maxln<<<16, DIM, 0, stream>>>(gd, gp, gamma1, beta1, gamma2, beta2, out);
}

// Round 2
// 153.868 us; speedup vs baseline: 2.5840x; 2.5840x over previous
//
#include <hip/hip_runtime.h>
#include <math.h>

#define B 8
#define LD 128
#define LP 1000
#define DIM 128
#define R 8                      // rows per GEMV block
#define LN_EPS 1e-5f

#define NBLK_D (B * LD / R)      // 128 drug blocks
#define NBLK_P (B * LP / R)      // 1000 protein blocks
#define SEG_D (NBLK_D / B)       // 16 partials per drug batch
#define SEG_P (NBLK_P / B)       // 125 partials per protein batch

// ---------------------------------------------------------------------------
// Kernel 1: fused GEMV for both drug and protein.
// Block handles R consecutive rows; thread t = output dim. Each thread reads
// its W row once per R rows (8x less L2 traffic on W than row-per-block).
// ---------------------------------------------------------------------------
__global__ void gemv_both(const float* __restrict__ Xd, const float* __restrict__ Xp,
                          const float* __restrict__ Wd, const float* __restrict__ bd,
                          const float* __restrict__ Wp, const float* __restrict__ bp,
                          float* __restrict__ outd, float* __restrict__ outp) {
    const int blk = blockIdx.x;
    const int t = threadIdx.x;

    const float *X, *W, *bias;
    float* out;
    int row0;
    if (blk < NBLK_D) { X = Xd; W = Wd; bias = bd; out = outd; row0 = blk * R; }
    else              { X = Xp; W = Wp; bias = bp; out = outp; row0 = (blk - NBLK_D) * R; }

    __shared__ float4 xs4[R][DIM / 4];
    float* xs = (float*)xs4;
#pragma unroll
    for (int r = 0; r < R; ++r) xs[r * DIM + t] = X[(row0 + r) * DIM + t];
    __syncthreads();

    float acc[R];
    const float bv = bias[t];
#pragma unroll
    for (int r = 0; r < R; ++r) acc[r] = bv;

    const float4* w4 = reinterpret_cast<const float4*>(W + t * DIM);
#pragma unroll
    for (int k = 0; k < DIM / 4; ++k) {
        const float4 w = w4[k];
#pragma unroll
        for (int r = 0; r < R; ++r) {
            const float4 x = xs4[r][k];    // LDS broadcast (all lanes same addr)
            acc[r] += w.x * x.x + w.y * x.y + w.z * x.z + w.w * x.w;
        }
    }
#pragma unroll
    for (int r = 0; r < R; ++r) out[(row0 + r) * DIM + t] = acc[r];
}

// ---------------------------------------------------------------------------
// Kernel 2: per (b,d): row/col mean of relu(x_i + y_j), i<LD, j<LP.
//   Mc[b,i,d] = (1/LP) * sum_j relu(x_i + y_j)
//   Mp[b,j,d] = (1/LD) * sum_i relu(x_i + y_j)
// ---------------------------------------------------------------------------
__global__ void pairwise(const float* __restrict__ d_att, const float* __restrict__ p_att,
                         float* __restrict__ Mc, float* __restrict__ Mp) {
    const int blk = blockIdx.x;
    const int b = blk >> 7;
    const int d = blk & (DIM - 1);
    const int t = threadIdx.x;

    __shared__ float xs[LD];
    __shared__ float ys[LP];
    __shared__ float red[256];

    for (int i = t; i < LD; i += 256) xs[i] = d_att[(b * LD + i) * DIM + d];
    for (int j = t; j < LP; j += 256) ys[j] = p_att[(b * LP + j) * DIM + d];
    __syncthreads();

    // column sums -> Mp
    for (int j = t; j < LP; j += 256) {
        const float y = ys[j];
        float s = 0.f;
#pragma unroll 8
        for (int i = 0; i < LD; ++i) s += fmaxf(0.f, xs[i] + y);
        Mp[(b * LP + j) * DIM + d] = s * (1.f / (float)LD);
    }

    // row sums -> Mc (two threads per row, 500 j's each)
    {
        const int r = t & (LD - 1);
        const int h = t >> 7;
        const float x = xs[r];
        float s = 0.f;
        const int j0 = h * (LP / 2);
#pragma unroll 4
        for (int jj = 0; jj < LP / 2; ++jj) s += fmaxf(0.f, x + ys[j0 + jj]);
        red[t] = s;
    }
    __syncthreads();
    if (t < LD) {
        Mc[(b * LD + t) * DIM + d] = (red[t] + red[t + LD]) * (1.f / (float)LP);
    }
}

// ---------------------------------------------------------------------------
// Kernel 3: gated GEMV + fused partial max.
//   val[row,t] = conv[row,t] * (0.5 + sigmoid(M[row] @ W_att^T + b_att)[t])
// Block reduces max over its R rows and writes ONE 128-float partial.
// The full gated tensor is never materialized.
// ---------------------------------------------------------------------------
__global__ void gated_both(const float* __restrict__ Mc, const float* __restrict__ Mp,
                           const float* __restrict__ W, const float* __restrict__ bias,
                           const float* __restrict__ convd, const float* __restrict__ convp,
                           float* __restrict__ pd, float* __restrict__ pp) {
    const int blk = blockIdx.x;
    const int t = threadIdx.x;

    const float *M, *conv;
    float* part;
    int row0;
    if (blk < NBLK_D) { M = Mc; conv = convd; part = pd + blk * DIM; row0 = blk * R; }
    else { const int pb = blk - NBLK_D; M = Mp; conv = convp; part = pp + pb * DIM; row0 = pb * R; }

    __shared__ float4 xs4[R][DIM / 4];
    float* xs = (float*)xs4;
#pragma unroll
    for (int r = 0; r < R; ++r) xs[r * DIM + t] = M[(row0 + r) * DIM + t];
    __syncthreads();

    float acc[R];
    const float bv = bias[t];
#pragma unroll
    for (int r = 0; r < R; ++r) acc[r] = bv;

    const float4* w4 = reinterpret_cast<const float4*>(W + t * DIM);
#pragma unroll
    for (int k = 0; k < DIM / 4; ++k) {
        const float4 w = w4[k];
#pragma unroll
        for (int r = 0; r < R; ++r) {
            const float4 x = xs4[r][k];
            acc[r] += w.x * x.x + w.y * x.y + w.z * x.z + w.w * x.w;
        }
    }

    float m = -INFINITY;
#pragma unroll
    for (int r = 0; r < R; ++r) {
        const float att = 1.f / (1.f + expf(-acc[r]));
        const float v = conv[(row0 + r) * DIM + t] * (0.5f + att);
        m = fmaxf(m, v);
    }
    part[t] = m;
}

// ---------------------------------------------------------------------------
// Kernel 4: reduce partials (16 or 125 per batch) + LayerNorm over DIM.
// ---------------------------------------------------------------------------
__global__ void maxln_final(const float* __restrict__ pd, const float* __restrict__ pp,
                            const float* __restrict__ gamma1, const float* __restrict__ beta1,
                            const float* __restrict__ gamma2, const float* __restrict__ beta2,
                            float* __restrict__ out) {
    const int blk = blockIdx.x;
    const int kind = blk >> 3;
    const int b = blk & 7;
    const int t = threadIdx.x;

    float m = -INFINITY;
    if (kind == 0) {
        const float* base = pd + b * SEG_D * DIM;
#pragma unroll
        for (int s = 0; s < SEG_D; ++s) m = fmaxf(m, base[s * DIM + t]);
    } else {
        const float* base = pp + b * SEG_P * DIM;
#pragma unroll 5
        for (int s = 0; s < SEG_P; ++s) m = fmaxf(m, base[s * DIM + t]);
    }

    __shared__ float s1[DIM];
    __shared__ float s2[DIM];
    s1[t] = m;
    s2[t] = m * m;
    __syncthreads();
    for (int off = DIM / 2; off > 0; off >>= 1) {
        if (t < off) { s1[t] += s1[t + off]; s2[t] += s2[t + off]; }
        __syncthreads();
    }
    const float mu = s1[0] * (1.f / (float)DIM);
    const float var = s2[0] * (1.f / (float)DIM) - mu * mu;
    const float inv = rsqrtf(var + LN_EPS);

    const float* gamma = kind ? gamma2 : gamma1;
    const float* beta  = kind ? beta2  : beta1;
    out[blk * DIM + t] = (m - mu) * inv * gamma[t] + beta[t];
}

// ---------------------------------------------------------------------------
extern "C" void kernel_launch(void* const* d_in, const int* in_sizes, int n_in,
                              void* d_out, int out_size, void* d_ws, size_t ws_size,
                              hipStream_t stream) {
    const float* drug_conv    = (const float*)d_in[0];
    const float* protein_conv = (const float*)d_in[1];
    const float* W_d   = (const float*)d_in[2];
    const float* b_d   = (const float*)d_in[3];
    const float* W_p   = (const float*)d_in[4];
    const float* b_p   = (const float*)d_in[5];
    const float* W_att = (const float*)d_in[6];
    const float* b_att = (const float*)d_in[7];
    const float* gamma1 = (const float*)d_in[8];
    const float* beta1  = (const float*)d_in[9];
    const float* gamma2 = (const float*)d_in[10];
    const float* beta2  = (const float*)d_in[11];
    float* out = (float*)d_out;

    // workspace layout (floats)
    float* ws = (float*)d_ws;
    const size_t n_datt = (size_t)B * LD * DIM;          // 131072
    const size_t n_patt = (size_t)B * LP * DIM;          // 1024000
    float* d_att = ws;
    float* p_att = ws + n_datt;
    float* Mc    = ws + n_datt + n_patt;
    float* Mp    = ws + n_datt + n_patt + n_datt;
    // partials alias the (dead after pairwise) d_att/p_att region
    float* pd = ws;                                      // NBLK_D*DIM = 16384
    float* pp = ws + (size_t)NBLK_D * DIM;               // NBLK_P*DIM = 128000

    gemv_both<<<NBLK_D + NBLK_P, DIM, 0, stream>>>(drug_conv, protein_conv,
                                                   W_d, b_d, W_p, b_p, d_att, p_att);
    pairwise<<<B * DIM, 256, 0, stream>>>(d_att, p_att, Mc, Mp);
    gated_both<<<NBLK_D + NBLK_P, DIM, 0, stream>>>(Mc, Mp, W_att, b_att,
                                                    drug_conv, protein_conv, pd, pp);
    maxln_final<<<16, DIM, 0, stream>>>(pd, pp, gamma1, beta1, gamma2, beta2, out);
}

// Round 3
// 145.553 us; speedup vs baseline: 2.7317x; 1.0571x over previous
//
#include <hip/hip_runtime.h>
#include <math.h>

#define B 8
#define LD 128
#define LP 1000
#define LP_PAD 1008              // pad y to multiple of 16 (8 slices x float2)
#define DIM 128
#define R 8                      // rows per GEMV block
#define LN_EPS 1e-5f

#define NBLK_D (B * LD / R)      // 128 drug blocks
#define NBLK_P (B * LP / R)      // 1000 protein blocks
#define SEG_D (NBLK_D / B)       // 16 partials per drug batch
#define SEG_P (NBLK_P / B)       // 125 partials per protein batch

// ---------------------------------------------------------------------------
// Kernel 1: fused GEMV for both drug and protein.  out = X @ W^T + b
// Block handles R consecutive rows; thread t = output dim.
// ---------------------------------------------------------------------------
__global__ __launch_bounds__(DIM) void gemv_both(
        const float* __restrict__ Xd, const float* __restrict__ Xp,
        const float* __restrict__ Wd, const float* __restrict__ bd,
        const float* __restrict__ Wp, const float* __restrict__ bp,
        float* __restrict__ outd, float* __restrict__ outp) {
    const int blk = blockIdx.x;
    const int t = threadIdx.x;

    const float *X, *W, *bias;
    float* out;
    int row0;
    if (blk < NBLK_D) { X = Xd; W = Wd; bias = bd; out = outd; row0 = blk * R; }
    else              { X = Xp; W = Wp; bias = bp; out = outp; row0 = (blk - NBLK_D) * R; }

    __shared__ float4 xs4[R][DIM / 4];
    {   // vectorized staging: R*DIM floats = 256 float4, 2 per thread
        const float4* Xv = reinterpret_cast<const float4*>(X + (size_t)row0 * DIM);
        float4* s = (float4*)xs4;
        s[t] = Xv[t];
        s[t + DIM] = Xv[t + DIM];
    }
    __syncthreads();

    float acc[R];
    const float bv = bias[t];
#pragma unroll
    for (int r = 0; r < R; ++r) acc[r] = bv;

    const float4* w4 = reinterpret_cast<const float4*>(W + t * DIM);
#pragma unroll
    for (int k = 0; k < DIM / 4; ++k) {
        const float4 w = w4[k];
#pragma unroll
        for (int r = 0; r < R; ++r) {
            const float4 x = xs4[r][k];    // LDS broadcast
            acc[r] += w.x * x.x + w.y * x.y + w.z * x.z + w.w * x.w;
        }
    }
#pragma unroll
    for (int r = 0; r < R; ++r) out[(row0 + r) * DIM + t] = acc[r];
}

// ---------------------------------------------------------------------------
// Kernel 2: per (b,d): row/col mean of relu(x_i + y_j), i<LD, j<LP.
//   Mc[b,i,d] = (1/LP) * sum_j relu(x_i + y_j)
//   Mp[b,j,d] = (1/LD) * sum_i relu(x_i + y_j)
// Register-blocked: col pass = float2 y-pair in regs (1 LDS read / 2 cells),
// row pass = 4 rows in regs, float2 y reads (1 LDS read / 8 cells).
// Padding y with -1e30 makes relu contribute exactly 0 to row sums.
// ---------------------------------------------------------------------------
__global__ __launch_bounds__(256) void pairwise(
        const float* __restrict__ d_att, const float* __restrict__ p_att,
        float* __restrict__ Mc, float* __restrict__ Mp) {
    const int blk = blockIdx.x;
    const int b = blk >> 7;
    const int d = blk & (DIM - 1);
    const int t = threadIdx.x;

    __shared__ float xs[LD];
    __shared__ float2 ys2[LP_PAD / 2];
    __shared__ float red[LD * 8];

    if (t < LD) xs[t] = d_att[(b * LD + t) * DIM + d];
    for (int j = t; j < LP_PAD; j += 256) {
        ((float*)ys2)[j] = (j < LP) ? p_att[(b * LP + j) * DIM + d] : -1e30f;
    }
    __syncthreads();

    // ---- column sums -> Mp (each thread owns float2 pairs p = t, t+256)
    for (int p = t; p < LP_PAD / 2; p += 256) {
        const float2 y = ys2[p];
        float2 acc = make_float2(0.f, 0.f);
#pragma unroll 8
        for (int i = 0; i < LD; ++i) {
            const float x = xs[i];
            acc.x += fmaxf(0.f, x + y.x);
            acc.y += fmaxf(0.f, x + y.y);
        }
        const int j = 2 * p;
        if (j < LP)     Mp[(b * LP + j) * DIM + d]     = acc.x * (1.f / (float)LD);
        if (j + 1 < LP) Mp[(b * LP + j + 1) * DIM + d] = acc.y * (1.f / (float)LD);
    }

    // ---- row sums -> Mc (thread = 4 rows x 1/8 of y; 63 float2 reads each)
    {
        const int rq = t >> 3;           // row quad 0..31
        const int sl = t & 7;            // y slice 0..7
        const float x0 = xs[4 * rq + 0];
        const float x1 = xs[4 * rq + 1];
        const float x2 = xs[4 * rq + 2];
        const float x3 = xs[4 * rq + 3];
        float2 a0 = make_float2(0.f, 0.f), a1 = a0, a2 = a0, a3 = a0;
        for (int p = sl; p < LP_PAD / 2; p += 8) {
            const float2 y = ys2[p];
            a0.x += fmaxf(0.f, x0 + y.x); a0.y += fmaxf(0.f, x0 + y.y);
            a1.x += fmaxf(0.f, x1 + y.x); a1.y += fmaxf(0.f, x1 + y.y);
            a2.x += fmaxf(0.f, x2 + y.x); a2.y += fmaxf(0.f, x2 + y.y);
            a3.x += fmaxf(0.f, x3 + y.x); a3.y += fmaxf(0.f, x3 + y.y);
        }
        red[(4 * rq + 0) * 8 + sl] = a0.x + a0.y;
        red[(4 * rq + 1) * 8 + sl] = a1.x + a1.y;
        red[(4 * rq + 2) * 8 + sl] = a2.x + a2.y;
        red[(4 * rq + 3) * 8 + sl] = a3.x + a3.y;
    }
    __syncthreads();
    if (t < LD) {
        float s = 0.f;
#pragma unroll
        for (int k = 0; k < 8; ++k) s += red[t * 8 + k];
        Mc[(b * LD + t) * DIM + d] = s * (1.f / (float)LP);
    }
}

// ---------------------------------------------------------------------------
// Kernel 3: gated GEMV + fused partial max (never materializes gated tensor).
// ---------------------------------------------------------------------------
__global__ __launch_bounds__(DIM) void gated_both(
        const float* __restrict__ Mc, const float* __restrict__ Mp,
        const float* __restrict__ W, const float* __restrict__ bias,
        const float* __restrict__ convd, const float* __restrict__ convp,
        float* __restrict__ pd, float* __restrict__ pp) {
    const int blk = blockIdx.x;
    const int t = threadIdx.x;

    const float *M, *conv;
    float* part;
    int row0;
    if (blk < NBLK_D) { M = Mc; conv = convd; part = pd + blk * DIM; row0 = blk * R; }
    else { const int pb = blk - NBLK_D; M = Mp; conv = convp; part = pp + pb * DIM; row0 = pb * R; }

    __shared__ float4 xs4[R][DIM / 4];
    {
        const float4* Mv = reinterpret_cast<const float4*>(M + (size_t)row0 * DIM);
        float4* s = (float4*)xs4;
        s[t] = Mv[t];
        s[t + DIM] = Mv[t + DIM];
    }
    __syncthreads();

    float acc[R];
    const float bv = bias[t];
#pragma unroll
    for (int r = 0; r < R; ++r) acc[r] = bv;

    const float4* w4 = reinterpret_cast<const float4*>(W + t * DIM);
#pragma unroll
    for (int k = 0; k < DIM / 4; ++k) {
        const float4 w = w4[k];
#pragma unroll
        for (int r = 0; r < R; ++r) {
            const float4 x = xs4[r][k];
            acc[r] += w.x * x.x + w.y * x.y + w.z * x.z + w.w * x.w;
        }
    }

    float m = -INFINITY;
#pragma unroll
    for (int r = 0; r < R; ++r) {
        const float att = 1.f / (1.f + expf(-acc[r]));
        const float v = conv[(row0 + r) * DIM + t] * (0.5f + att);
        m = fmaxf(m, v);
    }
    part[t] = m;
}

// ---------------------------------------------------------------------------
// Kernel 4: reduce partials + LayerNorm.  256 threads: t = dim, h = seg half.
// ---------------------------------------------------------------------------
__global__ __launch_bounds__(256) void maxln_final(
        const float* __restrict__ pd, const float* __restrict__ pp,
        const float* __restrict__ gamma1, const float* __restrict__ beta1,
        const float* __restrict__ gamma2, const float* __restrict__ beta2,
        float* __restrict__ out) {
    const int blk = blockIdx.x;
    const int kind = blk >> 3;
    const int b = blk & 7;
    const int t = threadIdx.x & (DIM - 1);
    const int h = threadIdx.x >> 7;      // 0 or 1

    float m = -INFINITY;
    if (kind == 0) {
        const float* base = pd + b * SEG_D * DIM;
        for (int s = h; s < SEG_D; s += 2) m = fmaxf(m, base[s * DIM + t]);
    } else {
        const float* base = pp + b * SEG_P * DIM;
        for (int s = h; s < SEG_P; s += 2) m = fmaxf(m, base[s * DIM + t]);
    }

    __shared__ float sm[2][DIM];
    sm[h][t] = m;
    __syncthreads();

    __shared__ float s1[DIM];
    __shared__ float s2[DIM];
    if (threadIdx.x < DIM) {
        m = fmaxf(sm[0][t], sm[1][t]);
        sm[0][t] = m;                    // final max, reused below
        s1[t] = m;
        s2[t] = m * m;
    }
    __syncthreads();
    for (int off = DIM / 2; off > 0; off >>= 1) {
        if (threadIdx.x < off) {
            s1[threadIdx.x] += s1[threadIdx.x + off];
            s2[threadIdx.x] += s2[threadIdx.x + off];
        }
        __syncthreads();
    }
    if (threadIdx.x < DIM) {
        const float mu = s1[0] * (1.f / (float)DIM);
        const float var = s2[0] * (1.f / (float)DIM) - mu * mu;
        const float inv = rsqrtf(var + LN_EPS);
        const float* gamma = kind ? gamma2 : gamma1;
        const float* beta  = kind ? beta2  : beta1;
        const float mv = sm[0][t];
        out[blk * DIM + t] = (mv - mu) * inv * gamma[t] + beta[t];
    }
}

// ---------------------------------------------------------------------------
extern "C" void kernel_launch(void* const* d_in, const int* in_sizes, int n_in,
                              void* d_out, int out_size, void* d_ws, size_t ws_size,
                              hipStream_t stream) {
    const float* drug_conv    = (const float*)d_in[0];
    const float* protein_conv = (const float*)d_in[1];
    const float* W_d   = (const float*)d_in[2];
    const float* b_d   = (const float*)d_in[3];
    const float* W_p   = (const float*)d_in[4];
    const float* b_p   = (const float*)d_in[5];
    const float* W_att = (const float*)d_in[6];
    const float* b_att = (const float*)d_in[7];
    const float* gamma1 = (const float*)d_in[8];
    const float* beta1  = (const float*)d_in[9];
    const float* gamma2 = (const float*)d_in[10];
    const float* beta2  = (const float*)d_in[11];
    float* out = (float*)d_out;

    float* ws = (float*)d_ws;
    const size_t n_datt = (size_t)B * LD * DIM;
    const size_t n_patt = (size_t)B * LP * DIM;
    float* d_att = ws;
    float* p_att = ws + n_datt;
    float* Mc    = ws + n_datt + n_patt;
    float* Mp    = ws + n_datt + n_patt + n_datt;
    float* pd = ws;                                   // alias dead d_att
    float* pp = ws + (size_t)NBLK_D * DIM;            // alias dead p_att

    gemv_both<<<NBLK_D + NBLK_P, DIM, 0, stream>>>(drug_conv, protein_conv,
                                                   W_d, b_d, W_p, b_p, d_att, p_att);
    pairwise<<<B * DIM, 256, 0, stream>>>(d_att, p_att, Mc, Mp);
    gated_both<<<NBLK_D + NBLK_P, DIM, 0, stream>>>(Mc, Mp, W_att, b_att,
                                                    drug_conv, protein_conv, pd, pp);
    maxln_final<<<16, 256, 0, stream>>>(pd, pp, gamma1, beta1, gamma2, beta2, out);
}

// Round 4
// 140.200 us; speedup vs baseline: 2.8360x; 1.0382x over previous
//
#include <hip/hip_runtime.h>
#include <math.h>

#define B 8
#define LD 128
#define LP 1000
#define LP_PAD 1008              // pad y to multiple of 16 (8 slices x float2)
#define DIM 128
#define LN_EPS 1e-5f

#define TILES_D (B * LD / 16)    // 64 drug 16-row tiles (exact)
#define TILES_P (B * LP / 16)    // 500 protein 16-row tiles (exact, row-space concat)
#define GTILES_D 64              // gated drug tiles (8 per batch, exact)
#define GTILES_PB 63             // gated protein tiles PER BATCH (63*16=1008 >= 1000)
#define GTILES_P (8 * GTILES_PB) // 504
#define SEG_D 8                  // drug partials per batch
#define SEG_P GTILES_PB          // protein partials per batch

typedef __attribute__((ext_vector_type(8))) short bf16x8;
typedef __attribute__((ext_vector_type(4))) float f32x4;

__device__ inline short f2bf(float f) {
    union { float f; unsigned u; } v; v.f = f;
    unsigned r = v.u + 0x7fffu + ((v.u >> 16) & 1u);   // RNE
    return (short)(r >> 16);
}

__device__ inline bf16x8 cvt8(float4 lo, float4 hi) {
    bf16x8 r;
    r[0] = f2bf(lo.x); r[1] = f2bf(lo.y); r[2] = f2bf(lo.z); r[3] = f2bf(lo.w);
    r[4] = f2bf(hi.x); r[5] = f2bf(hi.y); r[6] = f2bf(hi.z); r[7] = f2bf(hi.w);
    return r;
}

// ---------------------------------------------------------------------------
// Kernel 0: convert W_d, W_p, W_att (fp32 128x128 row-major) -> bf16.
// ---------------------------------------------------------------------------
__global__ __launch_bounds__(256) void conv_w(const float* __restrict__ W0,
                                              const float* __restrict__ W1,
                                              const float* __restrict__ W2,
                                              short* __restrict__ out) {
    const int idx = blockIdx.x * 256 + threadIdx.x;          // 0..49151
    const float* src = idx < 16384 ? W0 : (idx < 32768 ? W1 : W2);
    out[idx] = f2bf(src[idx & 16383]);
}

// ---------------------------------------------------------------------------
// Kernel 1: MFMA GEMV  out = X @ W^T + b  for drug (tiles 0..63) and protein
// (tiles 64..563). One wave = one 16-row tile, all 128 output cols.
// A-frag: X row (fp32->bf16 on the fly); B-frag: contiguous bf16x8 from W row.
// ---------------------------------------------------------------------------
__global__ __launch_bounds__(256) void mfma_gemv(
        const float* __restrict__ Xd, const float* __restrict__ Xp,
        const short* __restrict__ Wdb, const float* __restrict__ bd,
        const short* __restrict__ Wpb, const float* __restrict__ bp,
        float* __restrict__ outd, float* __restrict__ outp) {
    const int wave = (blockIdx.x * 256 + threadIdx.x) >> 6;
    const int lane = threadIdx.x & 63;

    const float* X; const short* Wb; const float* bias; float* out; int m0;
    if (wave < TILES_D) { X = Xd; Wb = Wdb; bias = bd; out = outd; m0 = wave * 16; }
    else { X = Xp; Wb = Wpb; bias = bp; out = outp; m0 = (wave - TILES_D) * 16; }

    const int arow = lane & 15;          // A row in tile / B col in tile
    const int kgrp = lane >> 4;          // k-group: k offset kgrp*8

    bf16x8 afrag[4];
    {
        const float* xrow = X + (size_t)(m0 + arow) * DIM + kgrp * 8;
#pragma unroll
        for (int kk = 0; kk < 4; ++kk)
            afrag[kk] = cvt8(*(const float4*)(xrow + kk * 32),
                             *(const float4*)(xrow + kk * 32 + 4));
    }

    const int ocol = lane & 15;
    const int orow = (lane >> 4) * 4;
#pragma unroll
    for (int nt = 0; nt < 8; ++nt) {
        const short* wrow = Wb + (size_t)(nt * 16 + arow) * DIM + kgrp * 8;
        f32x4 c = {0.f, 0.f, 0.f, 0.f};
#pragma unroll
        for (int kk = 0; kk < 4; ++kk) {
            const bf16x8 bfrag = *(const bf16x8*)(wrow + kk * 32);
            c = __builtin_amdgcn_mfma_f32_16x16x32_bf16(afrag[kk], bfrag, c, 0, 0, 0);
        }
        const float bv = bias[nt * 16 + ocol];
#pragma unroll
        for (int r = 0; r < 4; ++r)
            out[(size_t)(m0 + orow + r) * DIM + nt * 16 + ocol] = c[r] + bv;
    }
}

// ---------------------------------------------------------------------------
// Kernel 2: per (b,d): row/col mean of relu(x_i + y_j).  (unchanged)
// ---------------------------------------------------------------------------
__global__ __launch_bounds__(256) void pairwise(
        const float* __restrict__ d_att, const float* __restrict__ p_att,
        float* __restrict__ Mc, float* __restrict__ Mp) {
    const int blk = blockIdx.x;
    const int b = blk >> 7;
    const int d = blk & (DIM - 1);
    const int t = threadIdx.x;

    __shared__ float xs[LD];
    __shared__ float2 ys2[LP_PAD / 2];
    __shared__ float red[LD * 8];

    if (t < LD) xs[t] = d_att[(b * LD + t) * DIM + d];
    for (int j = t; j < LP_PAD; j += 256) {
        ((float*)ys2)[j] = (j < LP) ? p_att[(b * LP + j) * DIM + d] : -1e30f;
    }
    __syncthreads();

    for (int p = t; p < LP_PAD / 2; p += 256) {
        const float2 y = ys2[p];
        float2 acc = make_float2(0.f, 0.f);
#pragma unroll 8
        for (int i = 0; i < LD; ++i) {
            const float x = xs[i];
            acc.x += fmaxf(0.f, x + y.x);
            acc.y += fmaxf(0.f, x + y.y);
        }
        const int j = 2 * p;
        if (j < LP)     Mp[(b * LP + j) * DIM + d]     = acc.x * (1.f / (float)LD);
        if (j + 1 < LP) Mp[(b * LP + j + 1) * DIM + d] = acc.y * (1.f / (float)LD);
    }

    {
        const int rq = t >> 3;
        const int sl = t & 7;
        const float x0 = xs[4 * rq + 0];
        const float x1 = xs[4 * rq + 1];
        const float x2 = xs[4 * rq + 2];
        const float x3 = xs[4 * rq + 3];
        float2 a0 = make_float2(0.f, 0.f), a1 = a0, a2 = a0, a3 = a0;
        for (int p = sl; p < LP_PAD / 2; p += 8) {
            const float2 y = ys2[p];
            a0.x += fmaxf(0.f, x0 + y.x); a0.y += fmaxf(0.f, x0 + y.y);
            a1.x += fmaxf(0.f, x1 + y.x); a1.y += fmaxf(0.f, x1 + y.y);
            a2.x += fmaxf(0.f, x2 + y.x); a2.y += fmaxf(0.f, x2 + y.y);
            a3.x += fmaxf(0.f, x3 + y.x); a3.y += fmaxf(0.f, x3 + y.y);
        }
        red[(4 * rq + 0) * 8 + sl] = a0.x + a0.y;
        red[(4 * rq + 1) * 8 + sl] = a1.x + a1.y;
        red[(4 * rq + 2) * 8 + sl] = a2.x + a2.y;
        red[(4 * rq + 3) * 8 + sl] = a3.x + a3.y;
    }
    __syncthreads();
    if (t < LD) {
        float s = 0.f;
#pragma unroll
        for (int k = 0; k < 8; ++k) s += red[t * 8 + k];
        Mc[(b * LD + t) * DIM + d] = s * (1.f / (float)LP);
    }
}

// ---------------------------------------------------------------------------
// Kernel 3: MFMA gated GEMV + fused sigmoid gate * conv + per-tile column max.
// Drug: waves 0..63 (rows 16*w). Protein: waves 64..567, 63 tiles per batch,
// rows past 1000 in a batch masked to -INF.
// ---------------------------------------------------------------------------
__global__ __launch_bounds__(256) void mfma_gated(
        const float* __restrict__ Mc, const float* __restrict__ Mp,
        const short* __restrict__ Wb, const float* __restrict__ bias,
        const float* __restrict__ convd, const float* __restrict__ convp,
        float* __restrict__ pd, float* __restrict__ pp) {
    const int wave = (blockIdx.x * 256 + threadIdx.x) >> 6;
    const int lane = threadIdx.x & 63;

    const float* M; const float* conv; float* part; int m0; int valid;
    if (wave < GTILES_D) {
        M = Mc; conv = convd; part = pd + wave * DIM; m0 = wave * 16; valid = 16;
    } else {
        const int pb = wave - GTILES_D;
        const int b = pb / GTILES_PB;
        const int s = pb - b * GTILES_PB;
        M = Mp; conv = convp; part = pp + pb * DIM;
        m0 = b * LP + s * 16;
        valid = (s * 16 + 16 <= LP) ? 16 : (LP - s * 16);
    }

    const int arow = lane & 15;
    const int kgrp = lane >> 4;

    bf16x8 afrag[4];
    if (arow < valid) {
        const float* mrow = M + (size_t)(m0 + arow) * DIM + kgrp * 8;
#pragma unroll
        for (int kk = 0; kk < 4; ++kk)
            afrag[kk] = cvt8(*(const float4*)(mrow + kk * 32),
                             *(const float4*)(mrow + kk * 32 + 4));
    } else {
        bf16x8 z;
#pragma unroll
        for (int j = 0; j < 8; ++j) z[j] = 0;
#pragma unroll
        for (int kk = 0; kk < 4; ++kk) afrag[kk] = z;
    }

    const int ocol = lane & 15;
    const int orow = (lane >> 4) * 4;
#pragma unroll
    for (int nt = 0; nt < 8; ++nt) {
        const short* wrow = Wb + (size_t)(nt * 16 + arow) * DIM + kgrp * 8;
        f32x4 c = {0.f, 0.f, 0.f, 0.f};
#pragma unroll
        for (int kk = 0; kk < 4; ++kk) {
            const bf16x8 bfrag = *(const bf16x8*)(wrow + kk * 32);
            c = __builtin_amdgcn_mfma_f32_16x16x32_bf16(afrag[kk], bfrag, c, 0, 0, 0);
        }
        const float bv = bias[nt * 16 + ocol];
        float m = -INFINITY;
#pragma unroll
        for (int r = 0; r < 4; ++r) {
            const int rr = orow + r;
            if (rr < valid) {
                const float att = 1.f / (1.f + __expf(-(c[r] + bv)));
                const float v = conv[(size_t)(m0 + rr) * DIM + nt * 16 + ocol] * (0.5f + att);
                m = fmaxf(m, v);
            }
        }
        m = fmaxf(m, __shfl_xor(m, 16));
        m = fmaxf(m, __shfl_xor(m, 32));
        if (lane < 16) part[nt * 16 + lane] = m;
    }
}

// ---------------------------------------------------------------------------
// Kernel 4: reduce partials + LayerNorm.  256 threads: t = dim, h = seg half.
// ---------------------------------------------------------------------------
__global__ __launch_bounds__(256) void maxln_final(
        const float* __restrict__ pd, const float* __restrict__ pp,
        const float* __restrict__ gamma1, const float* __restrict__ beta1,
        const float* __restrict__ gamma2, const float* __restrict__ beta2,
        float* __restrict__ out) {
    const int blk = blockIdx.x;
    const int kind = blk >> 3;
    const int b = blk & 7;
    const int t = threadIdx.x & (DIM - 1);
    const int h = threadIdx.x >> 7;

    float m = -INFINITY;
    if (kind == 0) {
        const float* base = pd + b * SEG_D * DIM;
        for (int s = h; s < SEG_D; s += 2) m = fmaxf(m, base[s * DIM + t]);
    } else {
        const float* base = pp + b * SEG_P * DIM;
        for (int s = h; s < SEG_P; s += 2) m = fmaxf(m, base[s * DIM + t]);
    }

    __shared__ float sm[2][DIM];
    sm[h][t] = m;
    __syncthreads();

    __shared__ float s1[DIM];
    __shared__ float s2[DIM];
    if (threadIdx.x < DIM) {
        m = fmaxf(sm[0][t], sm[1][t]);
        sm[0][t] = m;
        s1[t] = m;
        s2[t] = m * m;
    }
    __syncthreads();
    for (int off = DIM / 2; off > 0; off >>= 1) {
        if (threadIdx.x < off) {
            s1[threadIdx.x] += s1[threadIdx.x + off];
            s2[threadIdx.x] += s2[threadIdx.x + off];
        }
        __syncthreads();
    }
    if (threadIdx.x < DIM) {
        const float mu = s1[0] * (1.f / (float)DIM);
        const float var = s2[0] * (1.f / (float)DIM) - mu * mu;
        const float inv = rsqrtf(var + LN_EPS);
        const float* gamma = kind ? gamma2 : gamma1;
        const float* beta  = kind ? beta2  : beta1;
        out[blk * DIM + t] = (sm[0][t] - mu) * inv * gamma[t] + beta[t];
    }
}

// ---------------------------------------------------------------------------
extern "C" void kernel_launch(void* const* d_in, const int* in_sizes, int n_in,
                              void* d_out, int out_size, void* d_ws, size_t ws_size,
                              hipStream_t stream) {
    const float* drug_conv    = (const float*)d_in[0];
    const float* protein_conv = (const float*)d_in[1];
    const float* W_d   = (const float*)d_in[2];
    const float* b_d   = (const float*)d_in[3];
    const float* W_p   = (const float*)d_in[4];
    const float* b_p   = (const float*)d_in[5];
    const float* W_att = (const float*)d_in[6];
    const float* b_att = (const float*)d_in[7];
    const float* gamma1 = (const float*)d_in[8];
    const float* beta1  = (const float*)d_in[9];
    const float* gamma2 = (const float*)d_in[10];
    const float* beta2  = (const float*)d_in[11];
    float* out = (float*)d_out;

    // workspace layout (floats)
    float* ws = (float*)d_ws;
    const size_t n_datt = (size_t)B * LD * DIM;            // 131072
    const size_t n_patt = (size_t)B * LP * DIM;            // 1024000
    float* d_att = ws;                                     // [0, 131072)
    float* p_att = ws + n_datt;                            // [131072, 1155072)
    float* Mc    = ws + n_datt + n_patt;                   // [1155072, 1286144)
    float* Mp    = ws + n_datt + n_patt + n_datt;          // [1286144, 2310144)
    short* wbf   = (short*)(ws + 2310144);                 // 3*16384 bf16
    short* wb_d   = wbf;
    short* wb_p   = wbf + 16384;
    short* wb_att = wbf + 32768;
    // partials alias dead d_att/p_att region
    float* pd = ws;                                        // 64*128 = 8192
    float* pp = ws + GTILES_D * DIM;                       // 504*128 = 64512

    conv_w<<<192, 256, 0, stream>>>(W_d, W_p, W_att, wbf);
    mfma_gemv<<<(TILES_D + TILES_P) / 4, 256, 0, stream>>>(
        drug_conv, protein_conv, wb_d, b_d, wb_p, b_p, d_att, p_att);
    pairwise<<<B * DIM, 256, 0, stream>>>(d_att, p_att, Mc, Mp);
    mfma_gated<<<(GTILES_D + GTILES_P) / 4, 256, 0, stream>>>(
        Mc, Mp, wb_att, b_att, drug_conv, protein_conv, pd, pp);
    maxln_final<<<16, 256, 0, stream>>>(pd, pp, gamma1, beta1, gamma2, beta2, out);
}